// Round 12
// baseline (88.586 us; speedup 1.0000x reference)
//
#include <hip/hip_runtime.h>

// CosineSimilarityAttn on MI355X.
//   attn     = l2norm(K) @ l2norm(Q)^T              [4096,4096] f32
//   weighted = attn^T @ V  ==  Qn @ (Kn^T V)        [4096,1024] f32  (associativity)
// Pipeline (5 launches):
//   L1: norm(Q,K)->bf16 + i8(row-max quant, scales) + transpose v(f32->bf16)
//   L2: transpose kn -> knT
//   L3: CT partials = vbT * knT^T (128x64 tiles, split-K=4) -> weighted region
//   L4: gemm256_i8: [fused CT-reduce prologue] + attn = dequant(Kq8 Qq8^T)
//       256x128 tiles, 512 blocks = 2 blocks/CU, 3-buffer LDS ring, 1 barrier/tile
//   L5: weighted = Qn CT^T (overwrites the partials region last)

typedef unsigned short u16;
typedef unsigned int u32;
typedef unsigned char u8;
typedef float f32x4 __attribute__((ext_vector_type(4)));
typedef int int4v __attribute__((ext_vector_type(4)));
typedef __bf16 bf16x8 __attribute__((ext_vector_type(8)));

__device__ __forceinline__ u16 f2bf(float f) {
  u32 u = __builtin_bit_cast(u32, f);
  return (u16)((u + 0x7FFFu + ((u >> 16) & 1u)) >> 16);  // RNE
}

__device__ __forceinline__ void gload16(const u16* g, u16* l) {
  __builtin_amdgcn_global_load_lds((__attribute__((address_space(1))) void*)(void*)g,
                                   (__attribute__((address_space(3))) void*)(void*)l, 16, 0, 0);
}
__device__ __forceinline__ void gload16b(const u8* g, u8* l) {
  __builtin_amdgcn_global_load_lds((__attribute__((address_space(1))) void*)(void*)g,
                                   (__attribute__((address_space(3))) void*)(void*)l, 16, 0, 0);
}

#define BARRIER() __builtin_amdgcn_s_barrier()
#define WAITVM(n) asm volatile("s_waitcnt vmcnt(" #n ")" ::: "memory")
#define WAITLGKM0() do { asm volatile("s_waitcnt lgkmcnt(0)" ::: "memory"); \
                         __builtin_amdgcn_sched_barrier(0); } while (0)

// ---------------- L1: norm Q,K -> bf16 + i8(+scales) ; V-transpose ----------
__global__ __launch_bounds__(256) void norm_transv_kernel(
    const float* __restrict__ q, const float* __restrict__ k,
    u16* __restrict__ qnb, u16* __restrict__ knb,
    u8* __restrict__ qnq, u8* __restrict__ knq,
    float* __restrict__ sclQ, float* __restrict__ sclK,
    const float* __restrict__ v, u16* __restrict__ vbT) {
  int bid = blockIdx.x, t = threadIdx.x;
  if (bid < 8192) {
    const bool isQ = (bid < 4096);
    const float* src = isQ ? q : k;
    u16* dst = isQ ? qnb : knb;
    u8* dst8 = isQ ? qnq : knq;
    float* scl = isQ ? sclQ : sclK;
    int row = bid & 4095;
    const float4 val = ((const float4*)(src + (size_t)row * 1024))[t];
    float s = val.x * val.x + val.y * val.y + val.z * val.z + val.w * val.w;
    float am = fmaxf(fmaxf(fabsf(val.x), fabsf(val.y)), fmaxf(fabsf(val.z), fabsf(val.w)));
    #pragma unroll
    for (int off = 32; off > 0; off >>= 1) {
      s += __shfl_xor(s, off, 64);
      am = fmaxf(am, __shfl_xor(am, off, 64));
    }
    __shared__ float2 red[4];
    if ((t & 63) == 0) red[t >> 6] = make_float2(s, am);
    __syncthreads();
    float tot = red[0].x + red[1].x + red[2].x + red[3].x;
    float amall = fmaxf(fmaxf(red[0].y, red[1].y), fmaxf(red[2].y, red[3].y));
    float inv = 1.0f / fmaxf(sqrtf(tot), 1e-8f);
    float rm = fmaxf(amall * inv, 1e-30f);   // max |normalized element| in row
    float iq = 127.0f / rm;
    uint2 o;
    o.x = (u32)f2bf(val.x * inv) | ((u32)f2bf(val.y * inv) << 16);
    o.y = (u32)f2bf(val.z * inv) | ((u32)f2bf(val.w * inv) << 16);
    *(uint2*)(dst + (size_t)row * 1024 + t * 4) = o;
    int c0 = (int)rintf(val.x * inv * iq);
    int c1 = (int)rintf(val.y * inv * iq);
    int c2 = (int)rintf(val.z * inv * iq);
    int c3 = (int)rintf(val.w * inv * iq);
    u32 p = (u32)(c0 & 255) | ((u32)(c1 & 255) << 8) |
            ((u32)(c2 & 255) << 16) | ((u32)(c3 & 255) << 24);
    ((u32*)(dst8 + (size_t)row * 1024))[t] = p;
    if (t == 0) scl[row] = rm * (1.0f / 127.0f);
  } else {
    __shared__ __align__(16) float lds[64 * 64];
    int tix = bid - 8192;
    int r0 = (tix >> 4) * 64, c0 = (tix & 15) * 64;
    int ch = t & 15, lr = t >> 4;
    #pragma unroll
    for (int i = 0; i < 4; ++i) {
      int r = lr + i * 16;
      float4 val = *(const float4*)&v[(size_t)(r0 + r) * 1024 + c0 + ch * 4];
      int byteoff = r * 256 + ((ch * 16) ^ (((r >> 3) & 7) << 4));
      *(float4*)((char*)lds + byteoff) = val;
    }
    __syncthreads();
    int cch = t & 7, lrow = t >> 3;
    #pragma unroll
    for (int i = 0; i < 2; ++i) {
      int oc = lrow + i * 32;
      u16 vals[8];
      #pragma unroll
      for (int j = 0; j < 8; ++j) {
        int srl = cch * 8 + j;
        int byteoff = srl * 256 + (((oc >> 2) * 16) ^ (((srl >> 3) & 7) << 4)) + (oc & 3) * 4;
        vals[j] = f2bf(*(const float*)((const char*)lds + byteoff));
      }
      uint4 o;
      o.x = (u32)vals[0] | ((u32)vals[1] << 16);
      o.y = (u32)vals[2] | ((u32)vals[3] << 16);
      o.z = (u32)vals[4] | ((u32)vals[5] << 16);
      o.w = (u32)vals[6] | ((u32)vals[7] << 16);
      *(uint4*)&vbT[(size_t)(c0 + oc) * 4096 + r0 + cch * 8] = o;
    }
  }
}

// ---------------- L2: bf16 transpose knb [4096,1024] -> knT [1024,4096] --------
__global__ __launch_bounds__(256) void transpose_bf16_kernel(
    const u16* __restrict__ src, u16* __restrict__ dst) {
  int b = blockIdx.x;
  int r0 = (b >> 4) * 64, c0 = (b & 15) * 64;
  __shared__ __align__(16) u16 lds[64 * 64];
  int t = threadIdx.x;
  int lrow = t >> 3, cch = t & 7;
  #pragma unroll
  for (int i = 0; i < 2; ++i) {
    int sr = lrow + i * 32;
    uint4 val = *(const uint4*)&src[(size_t)(r0 + sr) * 1024 + c0 + cch * 8];
    int byteoff = sr * 128 + ((cch * 16) ^ (((sr >> 3) & 7) << 4));
    *(uint4*)((char*)lds + byteoff) = val;
  }
  __syncthreads();
  #pragma unroll
  for (int i = 0; i < 2; ++i) {
    int oc = lrow + i * 32;
    u16 vals[8];
    #pragma unroll
    for (int j = 0; j < 8; ++j) {
      int srl = cch * 8 + j;  // (srl>>3)&7 == cch
      int byteoff = srl * 128 + ((oc * 2) ^ (cch << 4));
      vals[j] = *(const u16*)((const char*)lds + byteoff);
    }
    uint4 o;
    o.x = (u32)vals[0] | ((u32)vals[1] << 16);
    o.y = (u32)vals[2] | ((u32)vals[3] << 16);
    o.z = (u32)vals[4] | ((u32)vals[5] << 16);
    o.w = (u32)vals[6] | ((u32)vals[7] << 16);
    *(uint4*)&dst[(size_t)(c0 + oc) * 4096 + r0 + cch * 8] = o;
  }
}

// ---------------- C = A * B^T, 2-phase double-buffered, frag-pipelined ---------
template<int BM, int BN, int MW, int NW>
__global__ __launch_bounds__(256) void gemm_abt(
    const u16* __restrict__ A, const u16* __restrict__ B, float* __restrict__ Cptr,
    int k_len, int lda, int ldb, int ldc, int plane) {
  static_assert(BM == 2 * MW * 16 && BN == 2 * NW * 16, "wave grid is 2x2");
  __shared__ __align__(16) u16 ldsA[2][BM * 64];
  __shared__ __align__(16) u16 ldsB[2][BN * 64];
  const int t = threadIdx.x, l = t & 63, w = t >> 6;
  const int tileM = blockIdx.y, tileN = blockIdx.x;
  const int k_start = blockIdx.z * k_len;
  Cptr += (size_t)blockIdx.z * plane;
  const int srow = l >> 3, schunk = (l & 7) * 8;
  const u16* gA = A + (size_t)(tileM * BM) * lda + k_start + schunk;
  const u16* gB = B + (size_t)(tileN * BN) * ldb + k_start + schunk;
  const int aoff = ((w >> 1) * MW * 16 + (l & 15)) * 64 + (l >> 4) * 8;
  const int boff = ((w & 1) * NW * 16 + (l & 15)) * 64 + (l >> 4) * 8;

  f32x4 acc[MW][NW];
  #pragma unroll
  for (int m = 0; m < MW; ++m)
    #pragma unroll
    for (int n = 0; n < NW; ++n) acc[m][n] = (f32x4){0.f, 0.f, 0.f, 0.f};

  auto stage = [&](int buf, int kof) {
    #pragma unroll
    for (int j = 0; j < BM / 32; ++j) {
      const int r = w * (BM / 4) + j * 8;
      gload16(gA + (size_t)(r + srow) * lda + kof, &ldsA[buf][r * 64]);
    }
    #pragma unroll
    for (int j = 0; j < BN / 32; ++j) {
      const int r = w * (BN / 4) + j * 8;
      gload16(gB + (size_t)(r + srow) * ldb + kof, &ldsB[buf][r * 64]);
    }
  };

  bf16x8 av0[MW], bv0[NW], av1[MW], bv1[NW];
  const int nt = k_len >> 6;
  stage(0, 0);
  __syncthreads();  // drains vmcnt(0): tile 0 landed in all waves
  #pragma unroll
  for (int m = 0; m < MW; ++m) av0[m] = *(const bf16x8*)&ldsA[0][aoff + m * 16 * 64];
  #pragma unroll
  for (int n = 0; n < NW; ++n) bv0[n] = *(const bf16x8*)&ldsB[0][boff + n * 16 * 64];

  for (int i = 0; i < nt; ++i) {
    const int cur = i & 1;
    if (i + 1 < nt) stage(cur ^ 1, (i + 1) * 64);  // in flight during MFMA below
    #pragma unroll
    for (int m = 0; m < MW; ++m) av1[m] = *(const bf16x8*)&ldsA[cur][aoff + m * 16 * 64 + 32];
    #pragma unroll
    for (int n = 0; n < NW; ++n) bv1[n] = *(const bf16x8*)&ldsB[cur][boff + n * 16 * 64 + 32];
    #pragma unroll
    for (int m = 0; m < MW; ++m)
      #pragma unroll
      for (int n = 0; n < NW; ++n)
        acc[m][n] = __builtin_amdgcn_mfma_f32_16x16x32_bf16(av0[m], bv0[n], acc[m][n], 0, 0, 0);
    #pragma unroll
    for (int m = 0; m < MW; ++m)
      #pragma unroll
      for (int n = 0; n < NW; ++n)
        acc[m][n] = __builtin_amdgcn_mfma_f32_16x16x32_bf16(av1[m], bv1[n], acc[m][n], 0, 0, 0);
    __syncthreads();  // consumption done + next tile's staging drained
    if (i + 1 < nt) {
      const int nxt = cur ^ 1;
      #pragma unroll
      for (int m = 0; m < MW; ++m) av0[m] = *(const bf16x8*)&ldsA[nxt][aoff + m * 16 * 64];
      #pragma unroll
      for (int n = 0; n < NW; ++n) bv0[n] = *(const bf16x8*)&ldsB[nxt][boff + n * 16 * 64];
    }
  }

  const int orow = tileM * BM + (w >> 1) * MW * 16 + (l >> 4) * 4;
  const int ocol = tileN * BN + (w & 1) * NW * 16 + (l & 15);
  #pragma unroll
  for (int m = 0; m < MW; ++m)
    #pragma unroll
    for (int n = 0; n < NW; ++n)
      #pragma unroll
      for (int r = 0; r < 4; ++r)
        Cptr[(size_t)(orow + m * 16 + r) * ldc + (ocol + n * 16)] = acc[m][n][r];
}

// ---------------- L4: 256x128-tile i8 GEMM (attn) + fused CT-reduce prologue ----
// attn = (Kq8 Qq8^T)_i32 * sk[row] * sq[col].  512 blocks (grid 32x16) at
// 2 blocks/CU (72 KiB LDS, <=128 VGPR): 4 waves/SIMD cross-hide ds_read/barrier
// bubbles. 3-buffer ring, ONE barrier per K-tile. Per thread per tile: 3
// gload16 (A lo/hi half + B). Hazards: STG(t+2) targets buf(t-1) whose last
// reads drained before barrier(t-1); pre-reads of (t+1) gated by vmcnt(3) +
// barrier (3 loads/STG -> newest 3 = t+2, waiting to 3 retires t+1's).
__global__ __launch_bounds__(512, 4) void gemm256_i8(
    const u8* __restrict__ A8, const u8* __restrict__ B8, float* __restrict__ C,
    const float* __restrict__ P, u16* __restrict__ ctred,
    const float* __restrict__ sclK, const float* __restrict__ sclQ, int ntn) {
  __shared__ __align__(16) u8 lds8[73728];  // 3 x 24 KiB ring {A:16K, B:8K}
  const int tid = threadIdx.x, l = tid & 63, w = tid >> 6;
  const int wm = w >> 2, wn = w & 3;
  const int nwg = gridDim.x * gridDim.y;     // 512, divisible by 8
  const int bid = blockIdx.y * gridDim.x + blockIdx.x;
  const int swz = (bid & 7) * (nwg >> 3) + (bid >> 3);
  const int tileM = swz / ntn, tileN = swz % ntn;

  // staging: slot q = tid; row = q>>2 (0..127), dest slot-in-row = q&3;
  // global src col = ((q&3) ^ ((row>>1)&3))*16 (pre-swizzled source, linear dest)
  const int offA = (tid >> 2) * 1024 + (((tid & 3) ^ ((tid >> 3) & 3)) << 4);
  const u8* gA8 = A8 + (size_t)tileM * 256 * 1024;
  const u8* gB8 = B8 + (size_t)tileN * 128 * 1024;

#define STG(kof, bb) do { \
    gload16b(gA8 + (kof) + offA,          lds8 + (bb) + w * 1024); \
    gload16b(gA8 + (kof) + offA + 131072, lds8 + (bb) + 8192 + w * 1024); \
    gload16b(gB8 + (kof) + offA,          lds8 + (bb) + 16384 + w * 1024); } while (0)

  // prologue: stage tiles 0,1 (6 loads)
  STG(0, 0);
  STG(64, 24576);
  // fused CT reduce (512 blocks x 2048 elems; independent buffers)
  {
    const int base = bid * 2048 + tid * 4;
    f32x4 s = *(const f32x4*)&P[base];
    #pragma unroll
    for (int p = 1; p < 4; ++p) s += *(const f32x4*)&P[(size_t)p * 1048576 + base];
    uint2 o;
    o.x = (u32)f2bf(s[0]) | ((u32)f2bf(s[1]) << 16);
    o.y = (u32)f2bf(s[2]) | ((u32)f2bf(s[3]) << 16);
    *(uint2*)&ctred[base] = o;
  }
  WAITVM(0);   // everything landed (once per kernel)
  BARRIER();

  // fragment offsets: row R = base + (l&15), k-slot l>>4, swizzled ^((l>>1)&3)
  const int scol = (((l >> 4) ^ ((l >> 1) & 3)) << 4);
  const int afragB = (wm * 128 + (l & 15)) * 64 + scol;          // + m*1024
  const int bfragB = 16384 + (wn * 32 + (l & 15)) * 64 + scol;   // + n*1024

  int4v acc[8][2];
  #pragma unroll
  for (int m = 0; m < 8; ++m)
    #pragma unroll
    for (int n = 0; n < 2; ++n) acc[m][n] = (int4v){0, 0, 0, 0};

  int4v A0[4], A1[4], B0[2];
  #pragma unroll
  for (int m = 0; m < 4; ++m) A0[m] = *(const int4v*)&lds8[afragB + m * 1024];
  #pragma unroll
  for (int n = 0; n < 2; ++n) B0[n] = *(const int4v*)&lds8[bfragB + n * 1024];

  const int NT = 16;
  for (int t = 0; t < NT; ++t) {
    const int bb = (t % 3) * 24576;
    if (t + 2 < NT) STG((t + 2) * 64, ((t + 2) % 3) * 24576);  // buf(t-1) is free
    WAITLGKM0();                        // pre-reads (A0,B0 of t) drained
    __builtin_amdgcn_s_setprio(1);
    #pragma unroll
    for (int m = 0; m < 4; ++m)
      #pragma unroll
      for (int n = 0; n < 2; ++n)
        acc[m][n] = __builtin_amdgcn_mfma_i32_16x16x64_i8(A0[m], B0[n], acc[m][n], 0, 0, 0);
    __builtin_amdgcn_s_setprio(0);
    #pragma unroll
    for (int m = 0; m < 4; ++m) A1[m] = *(const int4v*)&lds8[bb + afragB + (m + 4) * 1024];
    WAITLGKM0();
    __builtin_amdgcn_s_setprio(1);
    #pragma unroll
    for (int m = 0; m < 4; ++m)
      #pragma unroll
      for (int n = 0; n < 2; ++n)
        acc[m + 4][n] = __builtin_amdgcn_mfma_i32_16x16x64_i8(A1[m], B0[n], acc[m + 4][n], 0, 0, 0);
    __builtin_amdgcn_s_setprio(0);
    if (t + 1 < NT) {
      if (t + 2 < NT) { WAITVM(3); } else { WAITVM(0); }  // (t+1) staging landed
    }
    BARRIER();   // all waves: reads of buf(t) done AND (t+1) globally visible
    if (t + 1 < NT) {
      const int nb = ((t + 1) % 3) * 24576;
      #pragma unroll
      for (int m = 0; m < 4; ++m) A0[m] = *(const int4v*)&lds8[nb + afragB + m * 1024];
      #pragma unroll
      for (int n = 0; n < 2; ++n) B0[n] = *(const int4v*)&lds8[nb + bfragB + n * 1024];
    }
  }

  // epilogue: dequant + store. C/D layout: col = lane&15, row = (lane>>4)*4 + reg
  const int orow = tileM * 256 + wm * 128 + (l >> 4) * 4;
  const int ocol = tileN * 128 + wn * 32 + (l & 15);
  float sq[2];
  #pragma unroll
  for (int n = 0; n < 2; ++n) sq[n] = sclQ[ocol + n * 16];
  #pragma unroll
  for (int m = 0; m < 8; ++m) {
    const float4 sk4 = *(const float4*)&sclK[orow + m * 16];
    #pragma unroll
    for (int n = 0; n < 2; ++n)
      #pragma unroll
      for (int r = 0; r < 4; ++r)
        C[(size_t)(orow + m * 16 + r) * 4096 + (ocol + n * 16)] =
            (float)acc[m][n][r] * ((const float*)&sk4)[r] * sq[n];
  }
#undef STG
}

extern "C" void kernel_launch(void* const* d_in, const int* in_sizes, int n_in,
                              void* d_out, int out_size, void* d_ws, size_t ws_size,
                              hipStream_t stream) {
  const float* q = (const float*)d_in[0];
  const float* k = (const float*)d_in[1];
  const float* v = (const float*)d_in[2];
  float* out = (float*)d_out;
  float* weighted = out;                 // [4096,1024]; first holds CT partials (4x4MiB)
  float* attn = out + 4194304;           // [4096,4096]

  char* ws = (char*)d_ws;                // ~42.2 MiB used
  u16* qnb = (u16*)(ws);                 // Qn bf16 [4096,1024]   8 MiB
  u16* knb = (u16*)(ws + (8u << 20));    // Kn bf16 [4096,1024]   8 MiB
  u16* knT = (u16*)(ws + (16u << 20));   // Kn^T    [1024,4096]   8 MiB
  u16* vbT = (u16*)(ws + (24u << 20));   // V^T     [1024,4096]   8 MiB
  u16* ct  = (u16*)(ws + (32u << 20));   // CT bf16 [1024,1024]   2 MiB
  u8*  qnq = (u8*)(ws + (34u << 20));    // Qn i8   [4096,1024]   4 MiB
  u8*  knq = (u8*)(ws + (38u << 20));    // Kn i8   [4096,1024]   4 MiB
  float* sclQ = (float*)(ws + (42u << 20));            // 16 KiB
  float* sclK = (float*)(ws + (42u << 20) + 65536);    // 16 KiB

  norm_transv_kernel<<<9216, 256, 0, stream>>>(q, k, qnb, knb, qnq, knq, sclQ, sclK, v, vbT);
  transpose_bf16_kernel<<<1024, 256, 0, stream>>>(knb, knT);
  // CT partials = vbT * knT^T, split-K=4, planes in the weighted region (16 MiB)
  gemm_abt<128, 64, 4, 2><<<dim3(16, 8, 4), 256, 0, stream>>>(
      vbT, knT, weighted, 1024, 4096, 4096, 1024, 1048576);
  // attn = dequant(knq * qnq^T) with fused CT-reduce prologue (512 blocks, 2/CU)
  gemm256_i8<<<dim3(32, 16), 512, 0, stream>>>(
      knq, qnq, attn, weighted, ct, sclK, sclQ, 32);
  // weighted = qnb * ct^T : M=4096, N=1024, K=1024 (overwrites partials region)
  gemm_abt<128, 64, 4, 2><<<dim3(16, 32, 1), 256, 0, stream>>>(
      qnb, ct, weighted, 1024, 1024, 1024, 1024, 0);
}

// Round 13
// 88.282 us; speedup vs baseline: 1.0034x; 1.0034x over previous
//
#include <hip/hip_runtime.h>

// CosineSimilarityAttn on MI355X.
//   attn     = l2norm(K) @ l2norm(Q)^T              [4096,4096] f32
//   weighted = attn^T @ V  ==  Qn @ (Kn^T V)        [4096,1024] f32  (associativity)
// Pipeline (5 launches):
//   L1: norm(Q,K)->bf16 + i8(row-max quant, scales) + transpose v(f32->bf16)
//   L2: transpose kn -> knT
//   L3: CT partials = vbT * knT^T (128x64 tiles, split-K=4) -> weighted region
//   L4: gemm256_i8 (R11 structure): [fused CT-reduce prologue] + attn = dequant(Kq8 Qq8^T)
//   L5: weighted = Qn CT^T (overwrites the partials region last)
// gemm_abt (L3/L5) now uses a 3-buffer ring with RAW s_barrier + counted vmcnt
// (pattern validated by the R12 i8 kernel): __syncthreads' implicit vmcnt(0)
// drain removed -> staging stays in flight across barriers, prefetch depth 2.

typedef unsigned short u16;
typedef unsigned int u32;
typedef unsigned char u8;
typedef float f32x4 __attribute__((ext_vector_type(4)));
typedef int int4v __attribute__((ext_vector_type(4)));
typedef __bf16 bf16x8 __attribute__((ext_vector_type(8)));

__device__ __forceinline__ u16 f2bf(float f) {
  u32 u = __builtin_bit_cast(u32, f);
  return (u16)((u + 0x7FFFu + ((u >> 16) & 1u)) >> 16);  // RNE
}

__device__ __forceinline__ void gload16(const u16* g, u16* l) {
  __builtin_amdgcn_global_load_lds((__attribute__((address_space(1))) void*)(void*)g,
                                   (__attribute__((address_space(3))) void*)(void*)l, 16, 0, 0);
}
__device__ __forceinline__ void gload16b(const u8* g, u8* l) {
  __builtin_amdgcn_global_load_lds((__attribute__((address_space(1))) void*)(void*)g,
                                   (__attribute__((address_space(3))) void*)(void*)l, 16, 0, 0);
}

#define BARRIER() __builtin_amdgcn_s_barrier()
#define WAITVM(n) asm volatile("s_waitcnt vmcnt(" #n ")" ::: "memory")
#define WAITLGKM0() do { asm volatile("s_waitcnt lgkmcnt(0)" ::: "memory"); \
                         __builtin_amdgcn_sched_barrier(0); } while (0)

// ---------------- L1: norm Q,K -> bf16 + i8(+scales) ; V-transpose ----------
__global__ __launch_bounds__(256) void norm_transv_kernel(
    const float* __restrict__ q, const float* __restrict__ k,
    u16* __restrict__ qnb, u16* __restrict__ knb,
    u8* __restrict__ qnq, u8* __restrict__ knq,
    float* __restrict__ sclQ, float* __restrict__ sclK,
    const float* __restrict__ v, u16* __restrict__ vbT) {
  int bid = blockIdx.x, t = threadIdx.x;
  if (bid < 8192) {
    const bool isQ = (bid < 4096);
    const float* src = isQ ? q : k;
    u16* dst = isQ ? qnb : knb;
    u8* dst8 = isQ ? qnq : knq;
    float* scl = isQ ? sclQ : sclK;
    int row = bid & 4095;
    const float4 val = ((const float4*)(src + (size_t)row * 1024))[t];
    float s = val.x * val.x + val.y * val.y + val.z * val.z + val.w * val.w;
    float am = fmaxf(fmaxf(fabsf(val.x), fabsf(val.y)), fmaxf(fabsf(val.z), fabsf(val.w)));
    #pragma unroll
    for (int off = 32; off > 0; off >>= 1) {
      s += __shfl_xor(s, off, 64);
      am = fmaxf(am, __shfl_xor(am, off, 64));
    }
    __shared__ float2 red[4];
    if ((t & 63) == 0) red[t >> 6] = make_float2(s, am);
    __syncthreads();
    float tot = red[0].x + red[1].x + red[2].x + red[3].x;
    float amall = fmaxf(fmaxf(red[0].y, red[1].y), fmaxf(red[2].y, red[3].y));
    float inv = 1.0f / fmaxf(sqrtf(tot), 1e-8f);
    float rm = fmaxf(amall * inv, 1e-30f);   // max |normalized element| in row
    float iq = 127.0f / rm;
    uint2 o;
    o.x = (u32)f2bf(val.x * inv) | ((u32)f2bf(val.y * inv) << 16);
    o.y = (u32)f2bf(val.z * inv) | ((u32)f2bf(val.w * inv) << 16);
    *(uint2*)(dst + (size_t)row * 1024 + t * 4) = o;
    int c0 = (int)rintf(val.x * inv * iq);
    int c1 = (int)rintf(val.y * inv * iq);
    int c2 = (int)rintf(val.z * inv * iq);
    int c3 = (int)rintf(val.w * inv * iq);
    u32 p = (u32)(c0 & 255) | ((u32)(c1 & 255) << 8) |
            ((u32)(c2 & 255) << 16) | ((u32)(c3 & 255) << 24);
    ((u32*)(dst8 + (size_t)row * 1024))[t] = p;
    if (t == 0) scl[row] = rm * (1.0f / 127.0f);
  } else {
    __shared__ __align__(16) float lds[64 * 64];
    int tix = bid - 8192;
    int r0 = (tix >> 4) * 64, c0 = (tix & 15) * 64;
    int ch = t & 15, lr = t >> 4;
    #pragma unroll
    for (int i = 0; i < 4; ++i) {
      int r = lr + i * 16;
      float4 val = *(const float4*)&v[(size_t)(r0 + r) * 1024 + c0 + ch * 4];
      int byteoff = r * 256 + ((ch * 16) ^ (((r >> 3) & 7) << 4));
      *(float4*)((char*)lds + byteoff) = val;
    }
    __syncthreads();
    int cch = t & 7, lrow = t >> 3;
    #pragma unroll
    for (int i = 0; i < 2; ++i) {
      int oc = lrow + i * 32;
      u16 vals[8];
      #pragma unroll
      for (int j = 0; j < 8; ++j) {
        int srl = cch * 8 + j;
        int byteoff = srl * 256 + (((oc >> 2) * 16) ^ (((srl >> 3) & 7) << 4)) + (oc & 3) * 4;
        vals[j] = f2bf(*(const float*)((const char*)lds + byteoff));
      }
      uint4 o;
      o.x = (u32)vals[0] | ((u32)vals[1] << 16);
      o.y = (u32)vals[2] | ((u32)vals[3] << 16);
      o.z = (u32)vals[4] | ((u32)vals[5] << 16);
      o.w = (u32)vals[6] | ((u32)vals[7] << 16);
      *(uint4*)&vbT[(size_t)(c0 + oc) * 4096 + r0 + cch * 8] = o;
    }
  }
}

// ---------------- L2: bf16 transpose knb [4096,1024] -> knT [1024,4096] --------
__global__ __launch_bounds__(256) void transpose_bf16_kernel(
    const u16* __restrict__ src, u16* __restrict__ dst) {
  int b = blockIdx.x;
  int r0 = (b >> 4) * 64, c0 = (b & 15) * 64;
  __shared__ __align__(16) u16 lds[64 * 64];
  int t = threadIdx.x;
  int lrow = t >> 3, cch = t & 7;
  #pragma unroll
  for (int i = 0; i < 2; ++i) {
    int sr = lrow + i * 32;
    uint4 val = *(const uint4*)&src[(size_t)(r0 + sr) * 1024 + c0 + cch * 8];
    int byteoff = sr * 128 + ((cch * 16) ^ (((sr >> 3) & 7) << 4));
    *(uint4*)((char*)lds + byteoff) = val;
  }
  __syncthreads();
  #pragma unroll
  for (int i = 0; i < 2; ++i) {
    int oc = lrow + i * 32;
    u16 vals[8];
    #pragma unroll
    for (int j = 0; j < 8; ++j) {
      int srl = cch * 8 + j;  // (srl>>3)&7 == cch
      int byteoff = srl * 128 + ((oc * 2) ^ (cch << 4));
      vals[j] = *(const u16*)((const char*)lds + byteoff);
    }
    uint4 o;
    o.x = (u32)vals[0] | ((u32)vals[1] << 16);
    o.y = (u32)vals[2] | ((u32)vals[3] << 16);
    o.z = (u32)vals[4] | ((u32)vals[5] << 16);
    o.w = (u32)vals[6] | ((u32)vals[7] << 16);
    *(uint4*)&dst[(size_t)(c0 + oc) * 4096 + r0 + cch * 8] = o;
  }
}

// ---------------- C = A * B^T, 3-buffer ring, raw barriers + counted vmcnt -----
// Per iter: stage(t+2) into buf(t-1) [freed: all reads drained before
// barrier(t-1)] || read kk1(t) || MFMA kk0 -> MFMA kk1 -> vmcnt(6) [retires
// (t+1)'s 6 loads; newest 6 = (t+2)'s] -> s_barrier -> pre-read kk0(t+1).
// No vmcnt(0) drain at barriers (the m97 stall) — loads stay in flight.
template<int BM, int BN, int MW, int NW>
__global__ __launch_bounds__(256) void gemm_abt(
    const u16* __restrict__ A, const u16* __restrict__ B, float* __restrict__ Cptr,
    int k_len, int lda, int ldb, int ldc, int plane) {
  static_assert(BM == 2 * MW * 16 && BN == 2 * NW * 16, "wave grid is 2x2");
  static_assert(BM / 32 + BN / 32 == 6, "WAITVM(6) literal assumes 6 loads/thread/stage");
  constexpr int TILE = (BM + BN) * 64;           // u16 per ring slot (A then B)
  __shared__ __align__(16) u16 lds[3 * TILE];    // 72 KiB for <128,64>
  const int t = threadIdx.x, l = t & 63, w = t >> 6;
  const int tileM = blockIdx.y, tileN = blockIdx.x;
  const int k_start = blockIdx.z * k_len;
  Cptr += (size_t)blockIdx.z * plane;
  const int srow = l >> 3, schunk = (l & 7) * 8;
  const u16* gA = A + (size_t)(tileM * BM) * lda + k_start + schunk;
  const u16* gB = B + (size_t)(tileN * BN) * ldb + k_start + schunk;
  const int aoff = ((w >> 1) * MW * 16 + (l & 15)) * 64 + (l >> 4) * 8;
  const int boff = BM * 64 + ((w & 1) * NW * 16 + (l & 15)) * 64 + (l >> 4) * 8;

  f32x4 acc[MW][NW];
  #pragma unroll
  for (int m = 0; m < MW; ++m)
    #pragma unroll
    for (int n = 0; n < NW; ++n) acc[m][n] = (f32x4){0.f, 0.f, 0.f, 0.f};

  auto stage = [&](int buf, int kof) {
    u16* bb = lds + buf * TILE;
    #pragma unroll
    for (int j = 0; j < BM / 32; ++j) {
      const int r = w * (BM / 4) + j * 8;
      gload16(gA + (size_t)(r + srow) * lda + kof, bb + r * 64);
    }
    #pragma unroll
    for (int j = 0; j < BN / 32; ++j) {
      const int r = w * (BN / 4) + j * 8;
      gload16(gB + (size_t)(r + srow) * ldb + kof, bb + BM * 64 + r * 64);
    }
  };

  bf16x8 av0[MW], bv0[NW], av1[MW], bv1[NW];
  const int nt = k_len >> 6;
  stage(0, 0);
  if (nt > 1) { stage(1, 64); WAITVM(6); }   // newest 6 = tile1 -> tile0 landed
  else        { WAITVM(0); }
  BARRIER();                                  // all waves drained their tile-0 loads
  #pragma unroll
  for (int m = 0; m < MW; ++m) av0[m] = *(const bf16x8*)&lds[aoff + m * 16 * 64];
  #pragma unroll
  for (int n = 0; n < NW; ++n) bv0[n] = *(const bf16x8*)&lds[boff + n * 16 * 64];

  for (int i = 0; i < nt; ++i) {
    const u16* bb = lds + (i % 3) * TILE;
    if (i + 2 < nt) stage((i + 2) % 3, (i + 2) * 64);  // buf(i-1): reads drained
    // kk1 fragment reads (lgkm wait hides under the kk0 MFMA cluster)
    #pragma unroll
    for (int m = 0; m < MW; ++m) av1[m] = *(const bf16x8*)&bb[aoff + m * 16 * 64 + 32];
    #pragma unroll
    for (int n = 0; n < NW; ++n) bv1[n] = *(const bf16x8*)&bb[boff + n * 16 * 64 + 32];
    #pragma unroll
    for (int m = 0; m < MW; ++m)
      #pragma unroll
      for (int n = 0; n < NW; ++n)
        acc[m][n] = __builtin_amdgcn_mfma_f32_16x16x32_bf16(av0[m], bv0[n], acc[m][n], 0, 0, 0);
    #pragma unroll
    for (int m = 0; m < MW; ++m)
      #pragma unroll
      for (int n = 0; n < NW; ++n)
        acc[m][n] = __builtin_amdgcn_mfma_f32_16x16x32_bf16(av1[m], bv1[n], acc[m][n], 0, 0, 0);
    if (i + 1 < nt) {
      if (i + 2 < nt) { WAITVM(6); } else { WAITVM(0); }  // (i+1) staging landed
    }
    BARRIER();   // all waves: reads of buf(i) retired AND (i+1) globally visible
    if (i + 1 < nt) {
      const u16* nb = lds + ((i + 1) % 3) * TILE;
      #pragma unroll
      for (int m = 0; m < MW; ++m) av0[m] = *(const bf16x8*)&nb[aoff + m * 16 * 64];
      #pragma unroll
      for (int n = 0; n < NW; ++n) bv0[n] = *(const bf16x8*)&nb[boff + n * 16 * 64];
    }
  }

  const int orow = tileM * BM + (w >> 1) * MW * 16 + (l >> 4) * 4;
  const int ocol = tileN * BN + (w & 1) * NW * 16 + (l & 15);
  #pragma unroll
  for (int m = 0; m < MW; ++m)
    #pragma unroll
    for (int n = 0; n < NW; ++n)
      #pragma unroll
      for (int r = 0; r < 4; ++r)
        Cptr[(size_t)(orow + m * 16 + r) * ldc + (ocol + n * 16)] = acc[m][n][r];
}

// ---------------- L4: 256x256-tile i8 GEMM (attn) + fused CT-reduce prologue ----
// R11 structure (best measured). attn = (Kq8 Qq8^T)_i32 * sk[row] * sq[col].
// mfma_i32_16x16x64_i8; 4 x 32 KiB ring; 256 blocks = 1 block/CU.
__global__ __launch_bounds__(512, 2) void gemm256_i8(
    const u8* __restrict__ A8, const u8* __restrict__ B8, float* __restrict__ C,
    const float* __restrict__ P, u16* __restrict__ ctred,
    const float* __restrict__ sclK, const float* __restrict__ sclQ, int ntn) {
  __shared__ __align__(16) u8 lds8[131072];  // 4 x 32 KiB ring
  const int tid = threadIdx.x, l = tid & 63, w = tid >> 6;
  const int wm = w >> 2, wn = w & 3;
  const int nwg = gridDim.x * gridDim.y;     // 256, divisible by 8
  const int bid = blockIdx.y * gridDim.x + blockIdx.x;
  const int swz = (bid & 7) * (nwg >> 3) + (bid >> 3);
  const int tileM = swz / ntn, tileN = swz % ntn;

  const int r0 = w * 32 + (l >> 2);
  const int s0 = ((l & 3) ^ ((l >> 3) & 3)) * 16;      // byte col (pre-swizzled src)
  const int offA = r0 * 1024 + s0;
  const u8* gA8 = A8 + (size_t)tileM * 256 * 1024;
  const u8* gB8 = B8 + (size_t)tileN * 256 * 1024;

#define STGA8(kof, bb) do { \
    gload16b(gA8 + (kof) + offA,          lds8 + (bb) + w * 2048); \
    gload16b(gA8 + (kof) + offA + 16384,  lds8 + (bb) + w * 2048 + 1024); } while (0)
#define STGB8(kof, bb) do { \
    gload16b(gB8 + (kof) + offA,          lds8 + (bb) + 16384 + w * 2048); \
    gload16b(gB8 + (kof) + offA + 16384,  lds8 + (bb) + 16384 + w * 2048 + 1024); } while (0)

  STGA8(0, 0);        STGB8(0, 0);
  STGA8(64, 32768);   STGB8(64, 32768);
  STGA8(128, 65536);  STGB8(128, 65536);
  STGA8(192, 98304);  STGB8(192, 98304);
  // fused CT reduce (independent buffers; drained by the WAITVM(0) below)
  {
    const int base = bid * 4096 + tid * 8;
    f32x4 sa = *(const f32x4*)&P[base];
    f32x4 sb = *(const f32x4*)&P[base + 4];
    #pragma unroll
    for (int p = 1; p < 4; ++p) {
      sa += *(const f32x4*)&P[(size_t)p * 1048576 + base];
      sb += *(const f32x4*)&P[(size_t)p * 1048576 + base + 4];
    }
    uint4 o;
    o.x = (u32)f2bf(sa[0]) | ((u32)f2bf(sa[1]) << 16);
    o.y = (u32)f2bf(sa[2]) | ((u32)f2bf(sa[3]) << 16);
    o.z = (u32)f2bf(sb[0]) | ((u32)f2bf(sb[1]) << 16);
    o.w = (u32)f2bf(sb[2]) | ((u32)f2bf(sb[3]) << 16);
    *(uint4*)&ctred[base] = o;
  }
  WAITVM(0);
  BARRIER();

  const int scol = ((l >> 4) ^ ((l >> 1) & 3)) * 16;
  const int afragB = (wm * 128 + (l & 15)) * 64 + scol;  // + m*1024
  const int bfragB = (wn * 64 + (l & 15)) * 64 + scol;   // + n*1024, B at +16384

  int4v acc[8][4];
  #pragma unroll
  for (int m = 0; m < 8; ++m)
    #pragma unroll
    for (int n = 0; n < 4; ++n) acc[m][n] = (int4v){0, 0, 0, 0};

  int4v A0[4], A1[4], B0[4];
  #pragma unroll
  for (int m = 0; m < 4; ++m) A0[m] = *(const int4v*)&lds8[afragB + m * 1024];
  #pragma unroll
  for (int n = 0; n < 4; ++n) B0[n] = *(const int4v*)&lds8[16384 + bfragB + n * 1024];

  const int NT = 16;
  for (int t = 0; t < NT; ++t) {
    const int bb = (t & 3) * 32768;
    const int koff = t * 64;
    #pragma unroll
    for (int m = 0; m < 4; ++m) A1[m] = *(const int4v*)&lds8[bb + afragB + (m + 4) * 1024];
    BARRIER();
    WAITLGKM0();
    __builtin_amdgcn_s_setprio(1);
    #pragma unroll
    for (int m = 0; m < 4; ++m)
      #pragma unroll
      for (int n = 0; n < 4; ++n)
        acc[m][n] = __builtin_amdgcn_mfma_i32_16x16x64_i8(A0[m], B0[n], acc[m][n], 0, 0, 0);
    __builtin_amdgcn_s_setprio(0);
    BARRIER();   // all waves' tile-t lgkm reads drained -> buf reusable
    if (t + 4 < NT) { STGA8(koff + 256, bb); STGB8(koff + 256, bb); }
    __builtin_amdgcn_s_setprio(1);
    #pragma unroll
    for (int m = 0; m < 4; ++m)
      #pragma unroll
      for (int n = 0; n < 4; ++n)
        acc[m + 4][n] = __builtin_amdgcn_mfma_i32_16x16x64_i8(A1[m], B0[n], acc[m + 4][n], 0, 0, 0);
    __builtin_amdgcn_s_setprio(0);
    if (t + 4 < NT)      { WAITVM(12); }
    else if (t + 3 < NT) { WAITVM(8); }
    else if (t + 2 < NT) { WAITVM(4); }
    else if (t + 1 < NT) { WAITVM(0); }
    BARRIER();
    if (t + 1 < NT) {
      const int nb = ((t + 1) & 3) * 32768;
      #pragma unroll
      for (int m = 0; m < 4; ++m) A0[m] = *(const int4v*)&lds8[nb + afragB + m * 1024];
      #pragma unroll
      for (int n = 0; n < 4; ++n) B0[n] = *(const int4v*)&lds8[nb + 16384 + bfragB + n * 1024];
    }
  }

  const int orow = tileM * 256 + wm * 128 + (l >> 4) * 4;
  const int ocol = tileN * 256 + wn * 64 + (l & 15);
  float sq[4];
  #pragma unroll
  for (int n = 0; n < 4; ++n) sq[n] = sclQ[ocol + n * 16];
  #pragma unroll
  for (int m = 0; m < 8; ++m) {
    const float4 sk4 = *(const float4*)&sclK[orow + m * 16];
    #pragma unroll
    for (int n = 0; n < 4; ++n)
      #pragma unroll
      for (int r = 0; r < 4; ++r)
        C[(size_t)(orow + m * 16 + r) * 4096 + (ocol + n * 16)] =
            (float)acc[m][n][r] * ((const float*)&sk4)[r] * sq[n];
  }
#undef STGA8
#undef STGB8
}

extern "C" void kernel_launch(void* const* d_in, const int* in_sizes, int n_in,
                              void* d_out, int out_size, void* d_ws, size_t ws_size,
                              hipStream_t stream) {
  const float* q = (const float*)d_in[0];
  const float* k = (const float*)d_in[1];
  const float* v = (const float*)d_in[2];
  float* out = (float*)d_out;
  float* weighted = out;                 // [4096,1024]; first holds CT partials (4x4MiB)
  float* attn = out + 4194304;           // [4096,4096]

  char* ws = (char*)d_ws;                // ~42.2 MiB used
  u16* qnb = (u16*)(ws);                 // Qn bf16 [4096,1024]   8 MiB
  u16* knb = (u16*)(ws + (8u << 20));    // Kn bf16 [4096,1024]   8 MiB
  u16* knT = (u16*)(ws + (16u << 20));   // Kn^T    [1024,4096]   8 MiB
  u16* vbT = (u16*)(ws + (24u << 20));   // V^T     [1024,4096]   8 MiB
  u16* ct  = (u16*)(ws + (32u << 20));   // CT bf16 [1024,1024]   2 MiB
  u8*  qnq = (u8*)(ws + (34u << 20));    // Qn i8   [4096,1024]   4 MiB
  u8*  knq = (u8*)(ws + (38u << 20));    // Kn i8   [4096,1024]   4 MiB
  float* sclQ = (float*)(ws + (42u << 20));            // 16 KiB
  float* sclK = (float*)(ws + (42u << 20) + 65536);    // 16 KiB

  norm_transv_kernel<<<9216, 256, 0, stream>>>(q, k, qnb, knb, qnq, knq, sclQ, sclK, v, vbT);
  transpose_bf16_kernel<<<1024, 256, 0, stream>>>(knb, knT);
  // CT partials = vbT * knT^T, split-K=4, planes in the weighted region (16 MiB)
  gemm_abt<128, 64, 4, 2><<<dim3(16, 8, 4), 256, 0, stream>>>(
      vbT, knT, weighted, 1024, 4096, 4096, 1024, 1048576);
  // attn = dequant(knq * qnq^T) with fused CT-reduce prologue (256 blocks, 1/CU)
  gemm256_i8<<<dim3(16, 16), 512, 0, stream>>>(
      knq, qnq, attn, weighted, ct, sclK, sclQ, 16);
  // weighted = qnb * ct^T : M=4096, N=1024, K=1024 (overwrites partials region)
  gemm_abt<128, 64, 4, 2><<<dim3(16, 32, 1), 256, 0, stream>>>(
      qnb, ct, weighted, 1024, 1024, 1024, 1024, 0);
}

// Round 14
// 83.576 us; speedup vs baseline: 1.0599x; 1.0563x over previous
//
#include <hip/hip_runtime.h>

// CosineSimilarityAttn on MI355X.
//   attn     = l2norm(K) @ l2norm(Q)^T              [4096,4096] f32
//   weighted = attn^T @ V  ==  Qn @ (Kn^T V)        [4096,1024] f32  (associativity)
// Pipeline (5 launches):
//   L1: norm(Q,K)->bf16 + i8(row-max quant, scales) + transpose v(f32->bf16)
//   L2: transpose kn -> knT
//   L3: CT partials = vbT * knT^T (128x64 tiles, split-K=4) -> weighted region
//   L4: gemm256_i8 (R11 structure): [fused CT-reduce prologue] + attn = dequant(Kq8 Qq8^T)
//   L5: weighted = Qn CT^T (overwrites the partials region last)
// gemm_abt: 3-buffer ring + counted vmcnt (R13) + NEW slot-XOR LDS swizzle
// (T2): linear [row][64] tiles were a 16-way bank conflict on ds_read_b128
// (R1 counters: 1.26e7 SQ_LDS_BANK_CONFLICT); with the ring's counted vmcnt
// the conflict is on the critical path (m252 regime gate) -> swizzle it.

typedef unsigned short u16;
typedef unsigned int u32;
typedef unsigned char u8;
typedef float f32x4 __attribute__((ext_vector_type(4)));
typedef int int4v __attribute__((ext_vector_type(4)));
typedef __bf16 bf16x8 __attribute__((ext_vector_type(8)));

__device__ __forceinline__ u16 f2bf(float f) {
  u32 u = __builtin_bit_cast(u32, f);
  return (u16)((u + 0x7FFFu + ((u >> 16) & 1u)) >> 16);  // RNE
}

__device__ __forceinline__ void gload16(const u16* g, u16* l) {
  __builtin_amdgcn_global_load_lds((__attribute__((address_space(1))) void*)(void*)g,
                                   (__attribute__((address_space(3))) void*)(void*)l, 16, 0, 0);
}
__device__ __forceinline__ void gload16b(const u8* g, u8* l) {
  __builtin_amdgcn_global_load_lds((__attribute__((address_space(1))) void*)(void*)g,
                                   (__attribute__((address_space(3))) void*)(void*)l, 16, 0, 0);
}

#define BARRIER() __builtin_amdgcn_s_barrier()
#define WAITVM(n) asm volatile("s_waitcnt vmcnt(" #n ")" ::: "memory")
#define WAITLGKM0() do { asm volatile("s_waitcnt lgkmcnt(0)" ::: "memory"); \
                         __builtin_amdgcn_sched_barrier(0); } while (0)

// ---------------- L1: norm Q,K -> bf16 + i8(+scales) ; V-transpose ----------
__global__ __launch_bounds__(256) void norm_transv_kernel(
    const float* __restrict__ q, const float* __restrict__ k,
    u16* __restrict__ qnb, u16* __restrict__ knb,
    u8* __restrict__ qnq, u8* __restrict__ knq,
    float* __restrict__ sclQ, float* __restrict__ sclK,
    const float* __restrict__ v, u16* __restrict__ vbT) {
  int bid = blockIdx.x, t = threadIdx.x;
  if (bid < 8192) {
    const bool isQ = (bid < 4096);
    const float* src = isQ ? q : k;
    u16* dst = isQ ? qnb : knb;
    u8* dst8 = isQ ? qnq : knq;
    float* scl = isQ ? sclQ : sclK;
    int row = bid & 4095;
    const float4 val = ((const float4*)(src + (size_t)row * 1024))[t];
    float s = val.x * val.x + val.y * val.y + val.z * val.z + val.w * val.w;
    float am = fmaxf(fmaxf(fabsf(val.x), fabsf(val.y)), fmaxf(fabsf(val.z), fabsf(val.w)));
    #pragma unroll
    for (int off = 32; off > 0; off >>= 1) {
      s += __shfl_xor(s, off, 64);
      am = fmaxf(am, __shfl_xor(am, off, 64));
    }
    __shared__ float2 red[4];
    if ((t & 63) == 0) red[t >> 6] = make_float2(s, am);
    __syncthreads();
    float tot = red[0].x + red[1].x + red[2].x + red[3].x;
    float amall = fmaxf(fmaxf(red[0].y, red[1].y), fmaxf(red[2].y, red[3].y));
    float inv = 1.0f / fmaxf(sqrtf(tot), 1e-8f);
    float rm = fmaxf(amall * inv, 1e-30f);   // max |normalized element| in row
    float iq = 127.0f / rm;
    uint2 o;
    o.x = (u32)f2bf(val.x * inv) | ((u32)f2bf(val.y * inv) << 16);
    o.y = (u32)f2bf(val.z * inv) | ((u32)f2bf(val.w * inv) << 16);
    *(uint2*)(dst + (size_t)row * 1024 + t * 4) = o;
    int c0 = (int)rintf(val.x * inv * iq);
    int c1 = (int)rintf(val.y * inv * iq);
    int c2 = (int)rintf(val.z * inv * iq);
    int c3 = (int)rintf(val.w * inv * iq);
    u32 p = (u32)(c0 & 255) | ((u32)(c1 & 255) << 8) |
            ((u32)(c2 & 255) << 16) | ((u32)(c3 & 255) << 24);
    ((u32*)(dst8 + (size_t)row * 1024))[t] = p;
    if (t == 0) scl[row] = rm * (1.0f / 127.0f);
  } else {
    __shared__ __align__(16) float lds[64 * 64];
    int tix = bid - 8192;
    int r0 = (tix >> 4) * 64, c0 = (tix & 15) * 64;
    int ch = t & 15, lr = t >> 4;
    #pragma unroll
    for (int i = 0; i < 4; ++i) {
      int r = lr + i * 16;
      float4 val = *(const float4*)&v[(size_t)(r0 + r) * 1024 + c0 + ch * 4];
      int byteoff = r * 256 + ((ch * 16) ^ (((r >> 3) & 7) << 4));
      *(float4*)((char*)lds + byteoff) = val;
    }
    __syncthreads();
    int cch = t & 7, lrow = t >> 3;
    #pragma unroll
    for (int i = 0; i < 2; ++i) {
      int oc = lrow + i * 32;
      u16 vals[8];
      #pragma unroll
      for (int j = 0; j < 8; ++j) {
        int srl = cch * 8 + j;
        int byteoff = srl * 256 + (((oc >> 2) * 16) ^ (((srl >> 3) & 7) << 4)) + (oc & 3) * 4;
        vals[j] = f2bf(*(const float*)((const char*)lds + byteoff));
      }
      uint4 o;
      o.x = (u32)vals[0] | ((u32)vals[1] << 16);
      o.y = (u32)vals[2] | ((u32)vals[3] << 16);
      o.z = (u32)vals[4] | ((u32)vals[5] << 16);
      o.w = (u32)vals[6] | ((u32)vals[7] << 16);
      *(uint4*)&vbT[(size_t)(c0 + oc) * 4096 + r0 + cch * 8] = o;
    }
  }
}

// ---------------- L2: bf16 transpose knb [4096,1024] -> knT [1024,4096] --------
__global__ __launch_bounds__(256) void transpose_bf16_kernel(
    const u16* __restrict__ src, u16* __restrict__ dst) {
  int b = blockIdx.x;
  int r0 = (b >> 4) * 64, c0 = (b & 15) * 64;
  __shared__ __align__(16) u16 lds[64 * 64];
  int t = threadIdx.x;
  int lrow = t >> 3, cch = t & 7;
  #pragma unroll
  for (int i = 0; i < 2; ++i) {
    int sr = lrow + i * 32;
    uint4 val = *(const uint4*)&src[(size_t)(r0 + sr) * 1024 + c0 + cch * 8];
    int byteoff = sr * 128 + ((cch * 16) ^ (((sr >> 3) & 7) << 4));
    *(uint4*)((char*)lds + byteoff) = val;
  }
  __syncthreads();
  #pragma unroll
  for (int i = 0; i < 2; ++i) {
    int oc = lrow + i * 32;
    u16 vals[8];
    #pragma unroll
    for (int j = 0; j < 8; ++j) {
      int srl = cch * 8 + j;  // (srl>>3)&7 == cch
      int byteoff = srl * 128 + ((oc * 2) ^ (cch << 4));
      vals[j] = *(const u16*)((const char*)lds + byteoff);
    }
    uint4 o;
    o.x = (u32)vals[0] | ((u32)vals[1] << 16);
    o.y = (u32)vals[2] | ((u32)vals[3] << 16);
    o.z = (u32)vals[4] | ((u32)vals[5] << 16);
    o.w = (u32)vals[6] | ((u32)vals[7] << 16);
    *(uint4*)&dst[(size_t)(c0 + oc) * 4096 + r0 + cch * 8] = o;
  }
}

// ---------------- C = A * B^T, 3-buffer ring + counted vmcnt + T2 swizzle ------
// LDS rows are 128 B (= 32 banks): linear layout made fragment b128 reads a
// 16-way conflict. Swizzle: slot' = slot ^ (row&7) over the 8x16B slots/row.
// Staging keeps a LINEAR LDS dest (global_load_lds constraint) and pre-swizzles
// the GLOBAL source chunk: lane l covers (row = l>>3, slot = l&7) and fetches
// global chunk (l&7)^(l>>3). Fragment reads: row = base + (l&15) (base%16==0,
// so row&7 == l&7); kk0 slot = (l>>4)^(l&7), kk1 slot = kk0^4. 16 lanes now
// spread over 8 slot-groups -> 2-way (free, m136).
template<int BM, int BN, int MW, int NW>
__global__ __launch_bounds__(256) void gemm_abt(
    const u16* __restrict__ A, const u16* __restrict__ B, float* __restrict__ Cptr,
    int k_len, int lda, int ldb, int ldc, int plane) {
  static_assert(BM == 2 * MW * 16 && BN == 2 * NW * 16, "wave grid is 2x2");
  static_assert(BM / 32 + BN / 32 == 6, "WAITVM(6) literal assumes 6 loads/thread/stage");
  constexpr int TILE = (BM + BN) * 64;           // u16 per ring slot (A then B)
  __shared__ __align__(16) u16 lds[3 * TILE];    // 72 KiB for <128,64>
  const int t = threadIdx.x, l = t & 63, w = t >> 6;
  const int tileM = blockIdx.y, tileN = blockIdx.x;
  const int k_start = blockIdx.z * k_len;
  Cptr += (size_t)blockIdx.z * plane;
  const int srow = l >> 3;
  const int cswz = ((l & 7) ^ srow) * 8;         // pre-swizzled global chunk (u16)
  const u16* gA = A + (size_t)(tileM * BM) * lda + k_start + cswz;
  const u16* gB = B + (size_t)(tileN * BN) * ldb + k_start + cswz;
  // fragment element offsets (u16), swizzled k-slots
  const int slot0 = (l >> 4) ^ (l & 7);
  const int aoff0 = ((w >> 1) * MW * 16 + (l & 15)) * 64 + slot0 * 8;
  const int aoff1 = ((w >> 1) * MW * 16 + (l & 15)) * 64 + (slot0 ^ 4) * 8;
  const int boff0 = BM * 64 + ((w & 1) * NW * 16 + (l & 15)) * 64 + slot0 * 8;
  const int boff1 = BM * 64 + ((w & 1) * NW * 16 + (l & 15)) * 64 + (slot0 ^ 4) * 8;

  f32x4 acc[MW][NW];
  #pragma unroll
  for (int m = 0; m < MW; ++m)
    #pragma unroll
    for (int n = 0; n < NW; ++n) acc[m][n] = (f32x4){0.f, 0.f, 0.f, 0.f};

  auto stage = [&](int buf, int kof) {
    u16* bb = lds + buf * TILE;
    #pragma unroll
    for (int j = 0; j < BM / 32; ++j) {
      const int r = w * (BM / 4) + j * 8;
      gload16(gA + (size_t)(r + srow) * lda + kof, bb + r * 64);
    }
    #pragma unroll
    for (int j = 0; j < BN / 32; ++j) {
      const int r = w * (BN / 4) + j * 8;
      gload16(gB + (size_t)(r + srow) * ldb + kof, bb + BM * 64 + r * 64);
    }
  };

  bf16x8 av0[MW], bv0[NW], av1[MW], bv1[NW];
  const int nt = k_len >> 6;
  stage(0, 0);
  if (nt > 1) { stage(1, 64); WAITVM(6); }   // newest 6 = tile1 -> tile0 landed
  else        { WAITVM(0); }
  BARRIER();                                  // all waves drained their tile-0 loads
  #pragma unroll
  for (int m = 0; m < MW; ++m) av0[m] = *(const bf16x8*)&lds[aoff0 + m * 1024];
  #pragma unroll
  for (int n = 0; n < NW; ++n) bv0[n] = *(const bf16x8*)&lds[boff0 + n * 1024];

  for (int i = 0; i < nt; ++i) {
    const u16* bb = lds + (i % 3) * TILE;
    if (i + 2 < nt) stage((i + 2) % 3, (i + 2) * 64);  // buf(i-1): reads drained
    // kk1 fragment reads (lgkm wait hides under the kk0 MFMA cluster)
    #pragma unroll
    for (int m = 0; m < MW; ++m) av1[m] = *(const bf16x8*)&bb[aoff1 + m * 1024];
    #pragma unroll
    for (int n = 0; n < NW; ++n) bv1[n] = *(const bf16x8*)&bb[boff1 + n * 1024];
    #pragma unroll
    for (int m = 0; m < MW; ++m)
      #pragma unroll
      for (int n = 0; n < NW; ++n)
        acc[m][n] = __builtin_amdgcn_mfma_f32_16x16x32_bf16(av0[m], bv0[n], acc[m][n], 0, 0, 0);
    #pragma unroll
    for (int m = 0; m < MW; ++m)
      #pragma unroll
      for (int n = 0; n < NW; ++n)
        acc[m][n] = __builtin_amdgcn_mfma_f32_16x16x32_bf16(av1[m], bv1[n], acc[m][n], 0, 0, 0);
    if (i + 1 < nt) {
      if (i + 2 < nt) { WAITVM(6); } else { WAITVM(0); }  // (i+1) staging landed
    }
    BARRIER();   // all waves: reads of buf(i) retired AND (i+1) globally visible
    if (i + 1 < nt) {
      const u16* nb = lds + ((i + 1) % 3) * TILE;
      #pragma unroll
      for (int m = 0; m < MW; ++m) av0[m] = *(const bf16x8*)&nb[aoff0 + m * 1024];
      #pragma unroll
      for (int n = 0; n < NW; ++n) bv0[n] = *(const bf16x8*)&nb[boff0 + n * 1024];
    }
  }

  const int orow = tileM * BM + (w >> 1) * MW * 16 + (l >> 4) * 4;
  const int ocol = tileN * BN + (w & 1) * NW * 16 + (l & 15);
  #pragma unroll
  for (int m = 0; m < MW; ++m)
    #pragma unroll
    for (int n = 0; n < NW; ++n)
      #pragma unroll
      for (int r = 0; r < 4; ++r)
        Cptr[(size_t)(orow + m * 16 + r) * ldc + (ocol + n * 16)] = acc[m][n][r];
}

// ---------------- L4: 256x256-tile i8 GEMM (attn) + fused CT-reduce prologue ----
// R11 structure (best measured). attn = (Kq8 Qq8^T)_i32 * sk[row] * sq[col].
// mfma_i32_16x16x64_i8; 4 x 32 KiB ring; 256 blocks = 1 block/CU.
__global__ __launch_bounds__(512, 2) void gemm256_i8(
    const u8* __restrict__ A8, const u8* __restrict__ B8, float* __restrict__ C,
    const float* __restrict__ P, u16* __restrict__ ctred,
    const float* __restrict__ sclK, const float* __restrict__ sclQ, int ntn) {
  __shared__ __align__(16) u8 lds8[131072];  // 4 x 32 KiB ring
  const int tid = threadIdx.x, l = tid & 63, w = tid >> 6;
  const int wm = w >> 2, wn = w & 3;
  const int nwg = gridDim.x * gridDim.y;     // 256, divisible by 8
  const int bid = blockIdx.y * gridDim.x + blockIdx.x;
  const int swz = (bid & 7) * (nwg >> 3) + (bid >> 3);
  const int tileM = swz / ntn, tileN = swz % ntn;

  const int r0 = w * 32 + (l >> 2);
  const int s0 = ((l & 3) ^ ((l >> 3) & 3)) * 16;      // byte col (pre-swizzled src)
  const int offA = r0 * 1024 + s0;
  const u8* gA8 = A8 + (size_t)tileM * 256 * 1024;
  const u8* gB8 = B8 + (size_t)tileN * 256 * 1024;

#define STGA8(kof, bb) do { \
    gload16b(gA8 + (kof) + offA,          lds8 + (bb) + w * 2048); \
    gload16b(gA8 + (kof) + offA + 16384,  lds8 + (bb) + w * 2048 + 1024); } while (0)
#define STGB8(kof, bb) do { \
    gload16b(gB8 + (kof) + offA,          lds8 + (bb) + 16384 + w * 2048); \
    gload16b(gB8 + (kof) + offA + 16384,  lds8 + (bb) + 16384 + w * 2048 + 1024); } while (0)

  STGA8(0, 0);        STGB8(0, 0);
  STGA8(64, 32768);   STGB8(64, 32768);
  STGA8(128, 65536);  STGB8(128, 65536);
  STGA8(192, 98304);  STGB8(192, 98304);
  // fused CT reduce (independent buffers; drained by the WAITVM(0) below)
  {
    const int base = bid * 4096 + tid * 8;
    f32x4 sa = *(const f32x4*)&P[base];
    f32x4 sb = *(const f32x4*)&P[base + 4];
    #pragma unroll
    for (int p = 1; p < 4; ++p) {
      sa += *(const f32x4*)&P[(size_t)p * 1048576 + base];
      sb += *(const f32x4*)&P[(size_t)p * 1048576 + base + 4];
    }
    uint4 o;
    o.x = (u32)f2bf(sa[0]) | ((u32)f2bf(sa[1]) << 16);
    o.y = (u32)f2bf(sa[2]) | ((u32)f2bf(sa[3]) << 16);
    o.z = (u32)f2bf(sb[0]) | ((u32)f2bf(sb[1]) << 16);
    o.w = (u32)f2bf(sb[2]) | ((u32)f2bf(sb[3]) << 16);
    *(uint4*)&ctred[base] = o;
  }
  WAITVM(0);
  BARRIER();

  const int scol = ((l >> 4) ^ ((l >> 1) & 3)) * 16;
  const int afragB = (wm * 128 + (l & 15)) * 64 + scol;  // + m*1024
  const int bfragB = (wn * 64 + (l & 15)) * 64 + scol;   // + n*1024, B at +16384

  int4v acc[8][4];
  #pragma unroll
  for (int m = 0; m < 8; ++m)
    #pragma unroll
    for (int n = 0; n < 4; ++n) acc[m][n] = (int4v){0, 0, 0, 0};

  int4v A0[4], A1[4], B0[4];
  #pragma unroll
  for (int m = 0; m < 4; ++m) A0[m] = *(const int4v*)&lds8[afragB + m * 1024];
  #pragma unroll
  for (int n = 0; n < 4; ++n) B0[n] = *(const int4v*)&lds8[16384 + bfragB + n * 1024];

  const int NT = 16;
  for (int t = 0; t < NT; ++t) {
    const int bb = (t & 3) * 32768;
    const int koff = t * 64;
    #pragma unroll
    for (int m = 0; m < 4; ++m) A1[m] = *(const int4v*)&lds8[bb + afragB + (m + 4) * 1024];
    BARRIER();
    WAITLGKM0();
    __builtin_amdgcn_s_setprio(1);
    #pragma unroll
    for (int m = 0; m < 4; ++m)
      #pragma unroll
      for (int n = 0; n < 4; ++n)
        acc[m][n] = __builtin_amdgcn_mfma_i32_16x16x64_i8(A0[m], B0[n], acc[m][n], 0, 0, 0);
    __builtin_amdgcn_s_setprio(0);
    BARRIER();   // all waves' tile-t lgkm reads drained -> buf reusable
    if (t + 4 < NT) { STGA8(koff + 256, bb); STGB8(koff + 256, bb); }
    __builtin_amdgcn_s_setprio(1);
    #pragma unroll
    for (int m = 0; m < 4; ++m)
      #pragma unroll
      for (int n = 0; n < 4; ++n)
        acc[m + 4][n] = __builtin_amdgcn_mfma_i32_16x16x64_i8(A1[m], B0[n], acc[m + 4][n], 0, 0, 0);
    __builtin_amdgcn_s_setprio(0);
    if (t + 4 < NT)      { WAITVM(12); }
    else if (t + 3 < NT) { WAITVM(8); }
    else if (t + 2 < NT) { WAITVM(4); }
    else if (t + 1 < NT) { WAITVM(0); }
    BARRIER();
    if (t + 1 < NT) {
      const int nb = ((t + 1) & 3) * 32768;
      #pragma unroll
      for (int m = 0; m < 4; ++m) A0[m] = *(const int4v*)&lds8[nb + afragB + m * 1024];
      #pragma unroll
      for (int n = 0; n < 4; ++n) B0[n] = *(const int4v*)&lds8[nb + 16384 + bfragB + n * 1024];
    }
  }

  const int orow = tileM * 256 + wm * 128 + (l >> 4) * 4;
  const int ocol = tileN * 256 + wn * 64 + (l & 15);
  float sq[4];
  #pragma unroll
  for (int n = 0; n < 4; ++n) sq[n] = sclQ[ocol + n * 16];
  #pragma unroll
  for (int m = 0; m < 8; ++m) {
    const float4 sk4 = *(const float4*)&sclK[orow + m * 16];
    #pragma unroll
    for (int n = 0; n < 4; ++n)
      #pragma unroll
      for (int r = 0; r < 4; ++r)
        C[(size_t)(orow + m * 16 + r) * 4096 + (ocol + n * 16)] =
            (float)acc[m][n][r] * ((const float*)&sk4)[r] * sq[n];
  }
#undef STGA8
#undef STGB8
}

extern "C" void kernel_launch(void* const* d_in, const int* in_sizes, int n_in,
                              void* d_out, int out_size, void* d_ws, size_t ws_size,
                              hipStream_t stream) {
  const float* q = (const float*)d_in[0];
  const float* k = (const float*)d_in[1];
  const float* v = (const float*)d_in[2];
  float* out = (float*)d_out;
  float* weighted = out;                 // [4096,1024]; first holds CT partials (4x4MiB)
  float* attn = out + 4194304;           // [4096,4096]

  char* ws = (char*)d_ws;                // ~42.2 MiB used
  u16* qnb = (u16*)(ws);                 // Qn bf16 [4096,1024]   8 MiB
  u16* knb = (u16*)(ws + (8u << 20));    // Kn bf16 [4096,1024]   8 MiB
  u16* knT = (u16*)(ws + (16u << 20));   // Kn^T    [1024,4096]   8 MiB
  u16* vbT = (u16*)(ws + (24u << 20));   // V^T     [1024,4096]   8 MiB
  u16* ct  = (u16*)(ws + (32u << 20));   // CT bf16 [1024,1024]   2 MiB
  u8*  qnq = (u8*)(ws + (34u << 20));    // Qn i8   [4096,1024]   4 MiB
  u8*  knq = (u8*)(ws + (38u << 20));    // Kn i8   [4096,1024]   4 MiB
  float* sclQ = (float*)(ws + (42u << 20));            // 16 KiB
  float* sclK = (float*)(ws + (42u << 20) + 65536);    // 16 KiB

  norm_transv_kernel<<<9216, 256, 0, stream>>>(q, k, qnb, knb, qnq, knq, sclQ, sclK, v, vbT);
  transpose_bf16_kernel<<<1024, 256, 0, stream>>>(knb, knT);
  // CT partials = vbT * knT^T, split-K=4, planes in the weighted region (16 MiB)
  gemm_abt<128, 64, 4, 2><<<dim3(16, 8, 4), 256, 0, stream>>>(
      vbT, knT, weighted, 1024, 4096, 4096, 1024, 1048576);
  // attn = dequant(knq * qnq^T) with fused CT-reduce prologue (256 blocks, 1/CU)
  gemm256_i8<<<dim3(16, 16), 512, 0, stream>>>(
      knq, qnq, attn, weighted, ct, sclK, sclQ, 16);
  // weighted = qnb * ct^T : M=4096, N=1024, K=1024 (overwrites partials region)
  gemm_abt<128, 64, 4, 2><<<dim3(16, 32, 1), 256, 0, stream>>>(
      qnb, ct, weighted, 1024, 1024, 1024, 1024, 0);
}

// Round 15
// 82.496 us; speedup vs baseline: 1.0738x; 1.0131x over previous
//
#include <hip/hip_runtime.h>

// CosineSimilarityAttn on MI355X.
//   attn     = l2norm(K) @ l2norm(Q)^T              [4096,4096] f32
//   weighted = attn^T @ V  ==  Qn @ (Kn^T V)        [4096,1024] f32  (associativity)
// Pipeline (5 launches):
//   L1: norm(Q,K)->bf16 + i8(row-max quant, scales) + transpose v(f32->bf16)
//   L2: transpose kn -> knT
//   L3: CT partials = vbT * knT^T (128x64 tiles, split-K=4) -> weighted region
//   L4: gemm256_i8 BK=128: [fused CT-reduce prologue] + attn = dequant(Kq8 Qq8^T)
//       8 K-tiles of 64KB, double-buffered (128 KiB), staging spread across the
//       4 MFMA phases -> half the barriers of the BK=64 version at same occupancy
//   L5: weighted = Qn CT^T (overwrites the partials region last)

typedef unsigned short u16;
typedef unsigned int u32;
typedef unsigned char u8;
typedef float f32x4 __attribute__((ext_vector_type(4)));
typedef int int4v __attribute__((ext_vector_type(4)));
typedef __bf16 bf16x8 __attribute__((ext_vector_type(8)));

__device__ __forceinline__ u16 f2bf(float f) {
  u32 u = __builtin_bit_cast(u32, f);
  return (u16)((u + 0x7FFFu + ((u >> 16) & 1u)) >> 16);  // RNE
}

__device__ __forceinline__ void gload16(const u16* g, u16* l) {
  __builtin_amdgcn_global_load_lds((__attribute__((address_space(1))) void*)(void*)g,
                                   (__attribute__((address_space(3))) void*)(void*)l, 16, 0, 0);
}
__device__ __forceinline__ void gload16b(const u8* g, u8* l) {
  __builtin_amdgcn_global_load_lds((__attribute__((address_space(1))) void*)(void*)g,
                                   (__attribute__((address_space(3))) void*)(void*)l, 16, 0, 0);
}

#define BARRIER() __builtin_amdgcn_s_barrier()
#define WAITVM(n) asm volatile("s_waitcnt vmcnt(" #n ")" ::: "memory")
#define WAITLGKM0() do { asm volatile("s_waitcnt lgkmcnt(0)" ::: "memory"); \
                         __builtin_amdgcn_sched_barrier(0); } while (0)

// ---------------- L1: norm Q,K -> bf16 + i8(+scales) ; V-transpose ----------
__global__ __launch_bounds__(256) void norm_transv_kernel(
    const float* __restrict__ q, const float* __restrict__ k,
    u16* __restrict__ qnb, u16* __restrict__ knb,
    u8* __restrict__ qnq, u8* __restrict__ knq,
    float* __restrict__ sclQ, float* __restrict__ sclK,
    const float* __restrict__ v, u16* __restrict__ vbT) {
  int bid = blockIdx.x, t = threadIdx.x;
  if (bid < 8192) {
    const bool isQ = (bid < 4096);
    const float* src = isQ ? q : k;
    u16* dst = isQ ? qnb : knb;
    u8* dst8 = isQ ? qnq : knq;
    float* scl = isQ ? sclQ : sclK;
    int row = bid & 4095;
    const float4 val = ((const float4*)(src + (size_t)row * 1024))[t];
    float s = val.x * val.x + val.y * val.y + val.z * val.z + val.w * val.w;
    float am = fmaxf(fmaxf(fabsf(val.x), fabsf(val.y)), fmaxf(fabsf(val.z), fabsf(val.w)));
    #pragma unroll
    for (int off = 32; off > 0; off >>= 1) {
      s += __shfl_xor(s, off, 64);
      am = fmaxf(am, __shfl_xor(am, off, 64));
    }
    __shared__ float2 red[4];
    if ((t & 63) == 0) red[t >> 6] = make_float2(s, am);
    __syncthreads();
    float tot = red[0].x + red[1].x + red[2].x + red[3].x;
    float amall = fmaxf(fmaxf(red[0].y, red[1].y), fmaxf(red[2].y, red[3].y));
    float inv = 1.0f / fmaxf(sqrtf(tot), 1e-8f);
    float rm = fmaxf(amall * inv, 1e-30f);   // max |normalized element| in row
    float iq = 127.0f / rm;
    uint2 o;
    o.x = (u32)f2bf(val.x * inv) | ((u32)f2bf(val.y * inv) << 16);
    o.y = (u32)f2bf(val.z * inv) | ((u32)f2bf(val.w * inv) << 16);
    *(uint2*)(dst + (size_t)row * 1024 + t * 4) = o;
    int c0 = (int)rintf(val.x * inv * iq);
    int c1 = (int)rintf(val.y * inv * iq);
    int c2 = (int)rintf(val.z * inv * iq);
    int c3 = (int)rintf(val.w * inv * iq);
    u32 p = (u32)(c0 & 255) | ((u32)(c1 & 255) << 8) |
            ((u32)(c2 & 255) << 16) | ((u32)(c3 & 255) << 24);
    ((u32*)(dst8 + (size_t)row * 1024))[t] = p;
    if (t == 0) scl[row] = rm * (1.0f / 127.0f);
  } else {
    __shared__ __align__(16) float lds[64 * 64];
    int tix = bid - 8192;
    int r0 = (tix >> 4) * 64, c0 = (tix & 15) * 64;
    int ch = t & 15, lr = t >> 4;
    #pragma unroll
    for (int i = 0; i < 4; ++i) {
      int r = lr + i * 16;
      float4 val = *(const float4*)&v[(size_t)(r0 + r) * 1024 + c0 + ch * 4];
      int byteoff = r * 256 + ((ch * 16) ^ (((r >> 3) & 7) << 4));
      *(float4*)((char*)lds + byteoff) = val;
    }
    __syncthreads();
    int cch = t & 7, lrow = t >> 3;
    #pragma unroll
    for (int i = 0; i < 2; ++i) {
      int oc = lrow + i * 32;
      u16 vals[8];
      #pragma unroll
      for (int j = 0; j < 8; ++j) {
        int srl = cch * 8 + j;
        int byteoff = srl * 256 + (((oc >> 2) * 16) ^ (((srl >> 3) & 7) << 4)) + (oc & 3) * 4;
        vals[j] = f2bf(*(const float*)((const char*)lds + byteoff));
      }
      uint4 o;
      o.x = (u32)vals[0] | ((u32)vals[1] << 16);
      o.y = (u32)vals[2] | ((u32)vals[3] << 16);
      o.z = (u32)vals[4] | ((u32)vals[5] << 16);
      o.w = (u32)vals[6] | ((u32)vals[7] << 16);
      *(uint4*)&vbT[(size_t)(c0 + oc) * 4096 + r0 + cch * 8] = o;
    }
  }
}

// ---------------- L2: bf16 transpose knb [4096,1024] -> knT [1024,4096] --------
__global__ __launch_bounds__(256) void transpose_bf16_kernel(
    const u16* __restrict__ src, u16* __restrict__ dst) {
  int b = blockIdx.x;
  int r0 = (b >> 4) * 64, c0 = (b & 15) * 64;
  __shared__ __align__(16) u16 lds[64 * 64];
  int t = threadIdx.x;
  int lrow = t >> 3, cch = t & 7;
  #pragma unroll
  for (int i = 0; i < 2; ++i) {
    int sr = lrow + i * 32;
    uint4 val = *(const uint4*)&src[(size_t)(r0 + sr) * 1024 + c0 + cch * 8];
    int byteoff = sr * 128 + ((cch * 16) ^ (((sr >> 3) & 7) << 4));
    *(uint4*)((char*)lds + byteoff) = val;
  }
  __syncthreads();
  #pragma unroll
  for (int i = 0; i < 2; ++i) {
    int oc = lrow + i * 32;
    u16 vals[8];
    #pragma unroll
    for (int j = 0; j < 8; ++j) {
      int srl = cch * 8 + j;  // (srl>>3)&7 == cch
      int byteoff = srl * 128 + ((oc * 2) ^ (cch << 4));
      vals[j] = *(const u16*)((const char*)lds + byteoff);
    }
    uint4 o;
    o.x = (u32)vals[0] | ((u32)vals[1] << 16);
    o.y = (u32)vals[2] | ((u32)vals[3] << 16);
    o.z = (u32)vals[4] | ((u32)vals[5] << 16);
    o.w = (u32)vals[6] | ((u32)vals[7] << 16);
    *(uint4*)&dst[(size_t)(c0 + oc) * 4096 + r0 + cch * 8] = o;
  }
}

// ---------------- C = A * B^T, 3-buffer ring + counted vmcnt + T2 swizzle ------
template<int BM, int BN, int MW, int NW>
__global__ __launch_bounds__(256) void gemm_abt(
    const u16* __restrict__ A, const u16* __restrict__ B, float* __restrict__ Cptr,
    int k_len, int lda, int ldb, int ldc, int plane) {
  static_assert(BM == 2 * MW * 16 && BN == 2 * NW * 16, "wave grid is 2x2");
  static_assert(BM / 32 + BN / 32 == 6, "WAITVM(6) literal assumes 6 loads/thread/stage");
  constexpr int TILE = (BM + BN) * 64;           // u16 per ring slot (A then B)
  __shared__ __align__(16) u16 lds[3 * TILE];    // 72 KiB for <128,64>
  const int t = threadIdx.x, l = t & 63, w = t >> 6;
  const int tileM = blockIdx.y, tileN = blockIdx.x;
  const int k_start = blockIdx.z * k_len;
  Cptr += (size_t)blockIdx.z * plane;
  const int srow = l >> 3;
  const int cswz = ((l & 7) ^ srow) * 8;         // pre-swizzled global chunk (u16)
  const u16* gA = A + (size_t)(tileM * BM) * lda + k_start + cswz;
  const u16* gB = B + (size_t)(tileN * BN) * ldb + k_start + cswz;
  const int slot0 = (l >> 4) ^ (l & 7);
  const int aoff0 = ((w >> 1) * MW * 16 + (l & 15)) * 64 + slot0 * 8;
  const int aoff1 = ((w >> 1) * MW * 16 + (l & 15)) * 64 + (slot0 ^ 4) * 8;
  const int boff0 = BM * 64 + ((w & 1) * NW * 16 + (l & 15)) * 64 + slot0 * 8;
  const int boff1 = BM * 64 + ((w & 1) * NW * 16 + (l & 15)) * 64 + (slot0 ^ 4) * 8;

  f32x4 acc[MW][NW];
  #pragma unroll
  for (int m = 0; m < MW; ++m)
    #pragma unroll
    for (int n = 0; n < NW; ++n) acc[m][n] = (f32x4){0.f, 0.f, 0.f, 0.f};

  auto stage = [&](int buf, int kof) {
    u16* bb = lds + buf * TILE;
    #pragma unroll
    for (int j = 0; j < BM / 32; ++j) {
      const int r = w * (BM / 4) + j * 8;
      gload16(gA + (size_t)(r + srow) * lda + kof, bb + r * 64);
    }
    #pragma unroll
    for (int j = 0; j < BN / 32; ++j) {
      const int r = w * (BN / 4) + j * 8;
      gload16(gB + (size_t)(r + srow) * ldb + kof, bb + BM * 64 + r * 64);
    }
  };

  bf16x8 av0[MW], bv0[NW], av1[MW], bv1[NW];
  const int nt = k_len >> 6;
  stage(0, 0);
  if (nt > 1) { stage(1, 64); WAITVM(6); }   // newest 6 = tile1 -> tile0 landed
  else        { WAITVM(0); }
  BARRIER();
  #pragma unroll
  for (int m = 0; m < MW; ++m) av0[m] = *(const bf16x8*)&lds[aoff0 + m * 1024];
  #pragma unroll
  for (int n = 0; n < NW; ++n) bv0[n] = *(const bf16x8*)&lds[boff0 + n * 1024];

  for (int i = 0; i < nt; ++i) {
    const u16* bb = lds + (i % 3) * TILE;
    if (i + 2 < nt) stage((i + 2) % 3, (i + 2) * 64);
    #pragma unroll
    for (int m = 0; m < MW; ++m) av1[m] = *(const bf16x8*)&bb[aoff1 + m * 1024];
    #pragma unroll
    for (int n = 0; n < NW; ++n) bv1[n] = *(const bf16x8*)&bb[boff1 + n * 1024];
    #pragma unroll
    for (int m = 0; m < MW; ++m)
      #pragma unroll
      for (int n = 0; n < NW; ++n)
        acc[m][n] = __builtin_amdgcn_mfma_f32_16x16x32_bf16(av0[m], bv0[n], acc[m][n], 0, 0, 0);
    #pragma unroll
    for (int m = 0; m < MW; ++m)
      #pragma unroll
      for (int n = 0; n < NW; ++n)
        acc[m][n] = __builtin_amdgcn_mfma_f32_16x16x32_bf16(av1[m], bv1[n], acc[m][n], 0, 0, 0);
    if (i + 1 < nt) {
      if (i + 2 < nt) { WAITVM(6); } else { WAITVM(0); }
    }
    BARRIER();
    if (i + 1 < nt) {
      const u16* nb = lds + ((i + 1) % 3) * TILE;
      #pragma unroll
      for (int m = 0; m < MW; ++m) av0[m] = *(const bf16x8*)&nb[aoff0 + m * 1024];
      #pragma unroll
      for (int n = 0; n < NW; ++n) bv0[n] = *(const bf16x8*)&nb[boff0 + n * 1024];
    }
  }

  const int orow = tileM * BM + (w >> 1) * MW * 16 + (l >> 4) * 4;
  const int ocol = tileN * BN + (w & 1) * NW * 16 + (l & 15);
  #pragma unroll
  for (int m = 0; m < MW; ++m)
    #pragma unroll
    for (int n = 0; n < NW; ++n)
      #pragma unroll
      for (int r = 0; r < 4; ++r)
        Cptr[(size_t)(orow + m * 16 + r) * ldc + (ocol + n * 16)] = acc[m][n][r];
}

// ---------------- L4: 256x256-tile i8 GEMM, BK=128 + fused CT-reduce prologue --
// attn = (Kq8 Qq8^T)_i32 * sk[row] * sq[col].  8 K-tiles of 128 k-elems; per
// tile 64 KB staged (A 32K + B 32K), double-buffered = 128 KiB. Staging spread
// as 2 gload16 per MFMA phase (8/thread/tile); end-of-tile vmcnt(0)+barrier is
// cheap (loads issued >=3 phases earlier; inputs L2/L3-resident). Swizzle:
// slot' = slot ^ (row&7) over 8x16B slots/row; kk1 frag = kk0 byte ^ 64.
__global__ __launch_bounds__(512, 2) void gemm256_i8(
    const u8* __restrict__ A8, const u8* __restrict__ B8, float* __restrict__ C,
    const float* __restrict__ P, u16* __restrict__ ctred,
    const float* __restrict__ sclK, const float* __restrict__ sclQ, int ntn) {
  __shared__ __align__(16) u8 lds8[131072];  // 2 x {A 32K, B 32K}
  const int tid = threadIdx.x, l = tid & 63, w = tid >> 6;
  const int wm = w >> 2, wn = w & 3;
  const int nwg = gridDim.x * gridDim.y;     // 256, divisible by 8
  const int bid = blockIdx.y * gridDim.x + blockIdx.x;
  const int swz = (bid & 7) * (nwg >> 3) + (bid >> 3);
  const int tileM = swz / ntn, tileN = swz % ntn;

  // staging: chunk j covers rows w*8+64j+(l>>3), slot l&7; linear LDS dest
  // (wave-uniform base + lane*16), pre-swizzled global col = ((l&7)^(l>>3))*16
  const int srow8 = l >> 3;
  const int cswzB = ((l & 7) ^ srow8) * 16;
  const u8* gA8 = A8 + (size_t)tileM * 256 * 1024 + cswzB;
  const u8* gB8 = B8 + (size_t)tileN * 256 * 1024 + cswzB;

#define STGJ(j, koff, bb) do { \
    gload16b(gA8 + (size_t)(w * 8 + 64 * (j) + srow8) * 1024 + (koff), \
             lds8 + (bb) + w * 1024 + (j) * 8192); \
    gload16b(gB8 + (size_t)(w * 8 + 64 * (j) + srow8) * 1024 + (koff), \
             lds8 + (bb) + 32768 + w * 1024 + (j) * 8192); } while (0)

  // prologue: stage tile 0 (8 loads)
  STGJ(0, 0, 0); STGJ(1, 0, 0); STGJ(2, 0, 0); STGJ(3, 0, 0);
  // fused CT reduce (independent buffers; drained by the WAITVM(0) below)
  {
    const int base = bid * 4096 + tid * 8;
    f32x4 sa = *(const f32x4*)&P[base];
    f32x4 sb = *(const f32x4*)&P[base + 4];
    #pragma unroll
    for (int p = 1; p < 4; ++p) {
      sa += *(const f32x4*)&P[(size_t)p * 1048576 + base];
      sb += *(const f32x4*)&P[(size_t)p * 1048576 + base + 4];
    }
    uint4 o;
    o.x = (u32)f2bf(sa[0]) | ((u32)f2bf(sa[1]) << 16);
    o.y = (u32)f2bf(sa[2]) | ((u32)f2bf(sa[3]) << 16);
    o.z = (u32)f2bf(sb[0]) | ((u32)f2bf(sb[1]) << 16);
    o.w = (u32)f2bf(sb[2]) | ((u32)f2bf(sb[3]) << 16);
    *(uint4*)&ctred[base] = o;
  }
  WAITVM(0);
  BARRIER();

  // fragment offsets (bytes): row = base + (l&15) (row&7 == l&7);
  // kk0 slot' = (l>>4)^(l&7); kk1 = kk0 ^ 4 -> byte ^ 64
  const int fs = ((l >> 4) ^ (l & 7)) * 16;
  const int afrag0 = (wm * 128 + (l & 15)) * 128 + fs;           // + m*2048
  const int bfrag0 = 32768 + (wn * 64 + (l & 15)) * 128 + fs;    // + n*2048

  int4v acc[8][4];
  #pragma unroll
  for (int m = 0; m < 8; ++m)
    #pragma unroll
    for (int n = 0; n < 4; ++n) acc[m][n] = (int4v){0, 0, 0, 0};

#define MFMA16(AF, BF, MB) do { \
    __builtin_amdgcn_s_setprio(1); \
    _Pragma("unroll") \
    for (int m = 0; m < 4; ++m) { \
      _Pragma("unroll") \
      for (int n = 0; n < 4; ++n) \
        acc[(MB) + m][n] = __builtin_amdgcn_mfma_i32_16x16x64_i8(AF[m], BF[n], acc[(MB) + m][n], 0, 0, 0); \
    } \
    __builtin_amdgcn_s_setprio(0); } while (0)

  int4v A0[4], A1[4], B0[4], B1[4];
  #pragma unroll
  for (int m = 0; m < 4; ++m) A0[m] = *(const int4v*)&lds8[afrag0 + m * 2048];
  #pragma unroll
  for (int n = 0; n < 4; ++n) B0[n] = *(const int4v*)&lds8[bfrag0 + n * 2048];

  const int NT = 8;
  for (int t = 0; t < NT; ++t) {
    const int bb = (t & 1) << 16, nb = bb ^ 65536;
    const int nkoff = (t + 1) * 128;
    // ---- ph0: MFMA kk0 m0-3; read kk0 m4-7; stage chunk 0 ----
    if (t + 1 < NT) STGJ(0, nkoff, nb);
    #pragma unroll
    for (int m = 0; m < 4; ++m) A1[m] = *(const int4v*)&lds8[bb + (afrag0 + (m + 4) * 2048)];
    WAITLGKM0();
    MFMA16(A0, B0, 0);
    // ---- ph1: MFMA kk0 m4-7; read kk1 m0-3 + kk1 B; stage chunk 1 ----
    if (t + 1 < NT) STGJ(1, nkoff, nb);
    #pragma unroll
    for (int m = 0; m < 4; ++m) A0[m] = *(const int4v*)&lds8[bb + ((afrag0 ^ 64) + m * 2048)];
    #pragma unroll
    for (int n = 0; n < 4; ++n) B1[n] = *(const int4v*)&lds8[bb + ((bfrag0 ^ 64) + n * 2048)];
    WAITLGKM0();
    MFMA16(A1, B0, 4);
    // ---- ph2: MFMA kk1 m0-3; read kk1 m4-7; stage chunk 2 ----
    if (t + 1 < NT) STGJ(2, nkoff, nb);
    #pragma unroll
    for (int m = 0; m < 4; ++m) A1[m] = *(const int4v*)&lds8[bb + ((afrag0 ^ 64) + (m + 4) * 2048)];
    WAITLGKM0();
    MFMA16(A0, B1, 0);
    // ---- ph3: MFMA kk1 m4-7; stage chunk 3 ----
    if (t + 1 < NT) STGJ(3, nkoff, nb);
    MFMA16(A1, B1, 4);
    if (t + 1 < NT) {
      WAITVM(0);   // my 8 loads of t+1 landed (issued phases ago; L2-resident)
      BARRIER();   // all waves landed + all reads of bb retired
      #pragma unroll
      for (int m = 0; m < 4; ++m) A0[m] = *(const int4v*)&lds8[nb + (afrag0 + m * 2048)];
      #pragma unroll
      for (int n = 0; n < 4; ++n) B0[n] = *(const int4v*)&lds8[nb + (bfrag0 + n * 2048)];
    }
  }

  // epilogue: dequant + store. C/D layout: col = lane&15, row = (lane>>4)*4 + reg
  const int orow = tileM * 256 + wm * 128 + (l >> 4) * 4;
  const int ocol = tileN * 256 + wn * 64 + (l & 15);
  float sq[4];
  #pragma unroll
  for (int n = 0; n < 4; ++n) sq[n] = sclQ[ocol + n * 16];
  #pragma unroll
  for (int m = 0; m < 8; ++m) {
    const float4 sk4 = *(const float4*)&sclK[orow + m * 16];
    #pragma unroll
    for (int n = 0; n < 4; ++n)
      #pragma unroll
      for (int r = 0; r < 4; ++r)
        C[(size_t)(orow + m * 16 + r) * 4096 + (ocol + n * 16)] =
            (float)acc[m][n][r] * ((const float*)&sk4)[r] * sq[n];
  }
#undef STGJ
#undef MFMA16
}

extern "C" void kernel_launch(void* const* d_in, const int* in_sizes, int n_in,
                              void* d_out, int out_size, void* d_ws, size_t ws_size,
                              hipStream_t stream) {
  const float* q = (const float*)d_in[0];
  const float* k = (const float*)d_in[1];
  const float* v = (const float*)d_in[2];
  float* out = (float*)d_out;
  float* weighted = out;                 // [4096,1024]; first holds CT partials (4x4MiB)
  float* attn = out + 4194304;           // [4096,4096]

  char* ws = (char*)d_ws;                // ~42.2 MiB used
  u16* qnb = (u16*)(ws);                 // Qn bf16 [4096,1024]   8 MiB
  u16* knb = (u16*)(ws + (8u << 20));    // Kn bf16 [4096,1024]   8 MiB
  u16* knT = (u16*)(ws + (16u << 20));   // Kn^T    [1024,4096]   8 MiB
  u16* vbT = (u16*)(ws + (24u << 20));   // V^T     [1024,4096]   8 MiB
  u16* ct  = (u16*)(ws + (32u << 20));   // CT bf16 [1024,1024]   2 MiB
  u8*  qnq = (u8*)(ws + (34u << 20));    // Qn i8   [4096,1024]   4 MiB
  u8*  knq = (u8*)(ws + (38u << 20));    // Kn i8   [4096,1024]   4 MiB
  float* sclQ = (float*)(ws + (42u << 20));            // 16 KiB
  float* sclK = (float*)(ws + (42u << 20) + 65536);    // 16 KiB

  norm_transv_kernel<<<9216, 256, 0, stream>>>(q, k, qnb, knb, qnq, knq, sclQ, sclK, v, vbT);
  transpose_bf16_kernel<<<1024, 256, 0, stream>>>(knb, knT);
  // CT partials = vbT * knT^T, split-K=4, planes in the weighted region (16 MiB)
  gemm_abt<128, 64, 4, 2><<<dim3(16, 8, 4), 256, 0, stream>>>(
      vbT, knT, weighted, 1024, 4096, 4096, 1024, 1048576);
  // attn = dequant(knq * qnq^T) with fused CT-reduce prologue (256 blocks, 1/CU)
  gemm256_i8<<<dim3(16, 16), 512, 0, stream>>>(
      knq, qnq, attn, weighted, ct, sclK, sclQ, 16);
  // weighted = qnb * ct^T : M=4096, N=1024, K=1024 (overwrites partials region)
  gemm_abt<128, 64, 4, 2><<<dim3(16, 32, 1), 256, 0, stream>>>(
      qnb, ct, weighted, 1024, 1024, 1024, 1024, 0);
}